// Round 19
// baseline (298.468 us; speedup 1.0000x reference)
//
#include <hip/hip_runtime.h>
#include <hip/hip_bf16.h>

#define NN 100000
#define EE 1600000
#define ETOT 1700000   // EE + NN self loops
#define FIN1 128
#define HD 64
#define NC 10
#define NB 128
#define NEG 0.2f
#define LOG2E 1.44269504f

#define NBKT 196       // ceil(NN/512)
#define BCAP 10240     // per-bucket capacity (mean 8673, sd ~93)
#define BLKE 2048      // edges per bucketA block (4096->2048: 8-deep chains, 832 blocks)
#define ABLOCKS ((ETOT + BLKE - 1) / BLKE)   // 831
#define GBLOCKS ((NN + 63) / 64)             // 1563

// Input dtypes: floats fp32, integers int32 (harness spec; round-16 verified).

// workspace layout (bytes)
static constexpr size_t OFF_HA   = 0;                                // 6.4 MB
static constexpr size_t OFF_HB   = (size_t)NN * HD;                  // 6.4 MB
static constexpr size_t OFF_ESA  = (size_t)NN * HD * 2;
static constexpr size_t OFF_EDA  = OFF_ESA + (size_t)NN * 4;
static constexpr size_t OFF_ESB  = OFF_EDA + (size_t)NN * 4;
static constexpr size_t OFF_EDB  = OFF_ESB + (size_t)NN * 4;
static constexpr size_t OFF_ROW  = OFF_EDB + (size_t)NN * 4;         // rowptr[NN+1]
static constexpr size_t OFF_CSR  = OFF_ROW + (size_t)(NN + 4) * 4;   // 6.8 MB
static constexpr size_t OFF_GC   = OFF_CSR + (size_t)ETOT * 4;       // 1024 B
static constexpr size_t OFF_POOL = OFF_GC + 1024;                    // 32 KB (gcur+pooled: one memset)
static constexpr size_t OFF_BKT  = OFF_POOL + (size_t)NB * HD * 4;   // 8.03 MB
// total ~29.8 MB

typedef __attribute__((ext_vector_type(8))) short short8;   // 8 bf16 = 4 VGPR
typedef __attribute__((ext_vector_type(4))) float floatx4;
typedef __attribute__((ext_vector_type(2))) float floatx2;

__device__ __forceinline__ unsigned short f2bf(float f) {
  unsigned u = __float_as_uint(f);
  if ((u & 0x7F800000u) == 0x7F800000u) return (unsigned short)(u >> 16);
  return (unsigned short)((u + 0x7FFFu + ((u >> 16) & 1u)) >> 16);
}
__device__ __forceinline__ unsigned pk2(float a, float b) {
  return (unsigned)f2bf(a) | ((unsigned)f2bf(b) << 16);
}

// ---- fp8 e4m3 pack/unpack (HW builtins on gfx950; manual fallback) ----
#if __has_builtin(__builtin_amdgcn_cvt_pk_fp8_f32) && __has_builtin(__builtin_amdgcn_cvt_pk_f32_fp8)
#define HW_FP8 1
#endif
__device__ __forceinline__ unsigned enc1_fp8(float f) {
  _Float16 hf = (_Float16)f;
  unsigned short b = __builtin_bit_cast(unsigned short, hf);
  unsigned s = ((unsigned)b >> 8) & 0x80u;
  int mag = b & 0x7fff;
  if (mag < 0x2380) return s;
  int r = mag + 0x3F + ((mag >> 7) & 1);
  int m = (r >> 7) - 64;
  if (m > 0x7E) m = 0x7E;
  return s | (unsigned)m;
}
__device__ __forceinline__ unsigned pack4_fp8(float a, float b, float c, float d) {
#ifdef HW_FP8
  int w = __builtin_amdgcn_cvt_pk_fp8_f32(a, b, 0, false);
  w = __builtin_amdgcn_cvt_pk_fp8_f32(c, d, w, true);
  return (unsigned)w;
#else
  return enc1_fp8(a) | (enc1_fp8(b) << 8) | (enc1_fp8(c) << 16) | (enc1_fp8(d) << 24);
#endif
}
__device__ __forceinline__ float dec1_fp8(unsigned byte) {
  unsigned short hb = (unsigned short)(((byte & 0x80u) << 8) | ((byte & 0x7fu) << 7));
  _Float16 hf = __builtin_bit_cast(_Float16, hb);
  return (float)hf * 256.0f;
}
template <bool HI>
__device__ __forceinline__ floatx2 unpk2_fp8(unsigned w) {
#ifdef HW_FP8
  return __builtin_amdgcn_cvt_pk_f32_fp8((int)w, HI);
#else
  unsigned s = HI ? (w >> 16) : w;
  floatx2 r; r.x = dec1_fp8(s & 0xffu); r.y = dec1_fp8((s >> 8) & 0xffu);
  return r;
#endif
}

// ---------------- bucketA body (CSR phase 1) ----------------
__device__ __forceinline__ void bucketA_body(
    int bid, const int* __restrict__ EI, unsigned* __restrict__ bucketed,
    int* __restrict__ gcur, char* smem) {
  int* cnt = (int*)smem;
  int* base = cnt + NBKT;
  const int t = threadIdx.x;
  const long long start = (long long)bid * BLKE;
  unsigned pk[BLKE / 256];
  short bk[BLKE / 256];
  for (int i = t; i < NBKT; i += 256) cnt[i] = 0;
  __syncthreads();
#pragma unroll
  for (int j = 0; j < BLKE / 256; j++) {
    long long k = start + t + 256 * j;
    bk[j] = -1;
    if (k < ETOT) {
      int s, d;
      if (k < EE) { s = EI[k]; d = EI[(long long)EE + k]; }
      else        { s = d = (int)(k - EE); }
      int b = d >> 9;
      pk[j] = ((unsigned)s << 9) | (unsigned)(d & 511);
      bk[j] = (short)b;
      atomicAdd(&cnt[b], 1);
    }
  }
  __syncthreads();
  if (t < NBKT) {
    base[t] = (cnt[t] > 0) ? atomicAdd(&gcur[t], cnt[t]) : 0;
    cnt[t] = 0;
  }
  __syncthreads();
#pragma unroll
  for (int j = 0; j < BLKE / 256; j++) {
    if (bk[j] >= 0) {
      int b = bk[j];
      int pos = base[b] + atomicAdd(&cnt[b], 1);
      if (pos < BCAP) bucketed[(long long)b * BCAP + pos] = pk[j];
    }
  }
}

// ---------------- gemm1 body: h1 = x@W1^T from fp32 input (MFMA) ----------------
__device__ __forceinline__ void gemm1_body(
    int bid, const float* __restrict__ X, const float* __restrict__ W,
    const float* __restrict__ As, const float* __restrict__ Ad,
    unsigned* __restrict__ hout, float* __restrict__ es, float* __restrict__ ed,
    char* smem) {
  constexpr int K = FIN1, RW = K / 2;
  unsigned* Xw = (unsigned*)smem;             // 16 KB
  unsigned* Ww = (unsigned*)(smem + 16384);   // 16 KB
  const int t = threadIdx.x;
  const int nodeBase = bid * 64;

  for (int i4 = t * 4; i4 < 64 * K; i4 += 1024) {
    int node = i4 >> 7, k = i4 & (K - 1);
    float4 v = make_float4(0.f, 0.f, 0.f, 0.f);
    if (nodeBase + node < NN)
      v = *(const float4*)(X + ((long long)(nodeBase + node) << 7) + k);
    uint2 p = make_uint2(pk2(v.x, v.y), pk2(v.z, v.w));
    int kw = k >> 1;
    *(uint2*)&Xw[node * RW + (kw ^ ((node & 7) << 2))] = p;
  }
  for (int i4 = t * 4; i4 < 64 * K; i4 += 1024) {
    int f = i4 >> 7, k = i4 & (K - 1);
    float4 v = *(const float4*)(W + ((long long)f << 7) + k);
    uint2 p = make_uint2(pk2(v.x, v.y), pk2(v.z, v.w));
    int kw = k >> 1;
    *(uint2*)&Ww[f * RW + (kw ^ ((f & 7) << 2))] = p;
  }
  __syncthreads();

  const int w = t >> 6, l = t & 63, m = l & 15, q = l >> 4;
  const int nodeLoc = 16 * w + m;
  const int sxa = (nodeLoc & 7) << 2;
  floatx4 acc[4];
#pragma unroll
  for (int nt = 0; nt < 4; nt++) acc[nt] = (floatx4){0.f, 0.f, 0.f, 0.f};
#pragma unroll
  for (int kc = 0; kc < K; kc += 32) {
    const int kcw = (kc >> 1) + 4 * q;
    short8 af = *(const short8*)&Xw[nodeLoc * RW + (kcw ^ sxa)];
#pragma unroll
    for (int nt = 0; nt < 4; nt++) {
      int f = 16 * nt + m;
      short8 bf = *(const short8*)&Ww[f * RW + (kcw ^ ((f & 7) << 2))];
      acc[nt] = __builtin_amdgcn_mfma_f32_16x16x32_bf16(af, bf, acc[nt], 0, 0, 0);
    }
  }
  float asv[4], adv[4];
#pragma unroll
  for (int nt = 0; nt < 4; nt++) { asv[nt] = As[16 * nt + m]; adv[nt] = Ad[16 * nt + m]; }
#pragma unroll
  for (int r = 0; r < 4; r++) {
    float ss = 0.f, sd2 = 0.f;
#pragma unroll
    for (int nt = 0; nt < 4; nt++) {
      ss = fmaf(acc[nt][r], asv[nt], ss);
      sd2 = fmaf(acc[nt][r], adv[nt], sd2);
    }
#pragma unroll
    for (int off = 1; off < 16; off <<= 1) {
      ss += __shfl_xor(ss, off);
      sd2 += __shfl_xor(sd2, off);
    }
    if (m == 0) {
      int gn = nodeBase + 16 * w + 4 * q + r;
      if (gn < NN) { es[gn] = ss * LOG2E; ed[gn] = sd2 * LOG2E; }
    }
  }
  {
    int gn = nodeBase + 16 * w + 4 * q;
#pragma unroll
    for (int nt = 0; nt < 4; nt++) {
#pragma unroll
      for (int r = 0; r < 4; r++) {
        float v = acc[nt][r];
        float p1 = __shfl_xor(v, 1);
        float p2 = __shfl_xor(v, 2);
        float p3 = __shfl_xor(v, 3);
        if ((m & 3) == 0 && (gn + r) < NN)
          hout[(gn + r) * 16 + 4 * nt + (m >> 2)] = pack4_fp8(v, p1, p2, p3);
      }
    }
  }
}

// ---------------- fused dispatch: bucketA ∥ gemm1 (grid concatenation) ----------------
__global__ __launch_bounds__(256) void buildA_gemm1_kernel(
    const int* __restrict__ EI, unsigned* __restrict__ bucketed, int* __restrict__ gcur,
    const float* __restrict__ X, const float* __restrict__ W,
    const float* __restrict__ As, const float* __restrict__ Ad,
    unsigned* __restrict__ hout, float* __restrict__ es, float* __restrict__ ed) {
  __shared__ __align__(16) char smem[32768];
  if (blockIdx.x < ABLOCKS)
    bucketA_body(blockIdx.x, EI, bucketed, gcur, smem);
  else
    gemm1_body(blockIdx.x - ABLOCKS, X, W, As, Ad, hout, es, ed, smem);
}

// ---------------- bucketB: 1024 threads (4x latency hiding), inline scan ----------------
__global__ __launch_bounds__(1024) void bucketB_kernel(
    const unsigned* __restrict__ bucketed, const int* __restrict__ gcur,
    int* __restrict__ rowptr, int* __restrict__ csr) {
  __shared__ int sc[256];
  __shared__ int hist[512];
  __shared__ int cur[512];
  __shared__ int ssum[256];
  const int t = threadIdx.x;
  const int b = blockIdx.x;
  // inline exclusive scan of gcur (first 256 lanes; barriers convergent)
  if (t < 256) sc[t] = (t < NBKT) ? gcur[t] : 0;
  __syncthreads();
  for (int off = 1; off < 256; off <<= 1) {
    int add = (t >= off && t < 256) ? sc[t - off] : 0;
    __syncthreads();
    if (t < 256) sc[t] += add;
    __syncthreads();
  }
  const int cnt = gcur[b];
  const int base = sc[b] - cnt;
  if (b == 0 && t == 0) rowptr[NN] = ETOT;
  const unsigned* bp = bucketed + (long long)b * BCAP;
  if (t < 512) hist[t] = 0;
  __syncthreads();
  for (int i = t; i < cnt; i += 1024) atomicAdd(&hist[bp[i] & 511], 1);
  __syncthreads();
  int a0 = 0, a1 = 0, s = 0;
  if (t < 256) {
    a0 = hist[2 * t];
    a1 = hist[2 * t + 1];
    s = a0 + a1;
    ssum[t] = s;
  }
  __syncthreads();
  for (int off = 1; off < 256; off <<= 1) {
    int add = (t >= off && t < 256) ? ssum[t - off] : 0;
    __syncthreads();
    if (t < 256) ssum[t] += add;
    __syncthreads();
  }
  if (t < 256) {
    int ex = ssum[t] - s;
    cur[2 * t] = ex;
    cur[2 * t + 1] = ex + a0;
    int gn = b * 512 + 2 * t;
    if (gn < NN) rowptr[gn] = base + ex;
    if (gn + 1 < NN) rowptr[gn + 1] = base + ex + a0;
  }
  __syncthreads();
  for (int i = t; i < cnt; i += 1024) {
    unsigned e = bp[i];
    int pos = atomicAdd(&cur[e & 511], 1);
    csr[base + pos] = (int)(e >> 9);
  }
}

// ---------------- fused: aggregate layer L -> LDS -> gemm layer L+1 ----------------
__global__ __launch_bounds__(256) void agg_gemm_kernel(
    const int* __restrict__ rowptr, const int* __restrict__ csr,
    const float* __restrict__ esIn, const float* __restrict__ edIn,
    const uint2* __restrict__ h8In, const float* __restrict__ biasA,
    const float* __restrict__ W, const float* __restrict__ As,
    const float* __restrict__ Ad,
    unsigned* __restrict__ hOut, float* __restrict__ esOut, float* __restrict__ edOut) {
  constexpr int K = HD, RW = K / 2;   // 64, 32
  __shared__ unsigned Xw[64 * RW];
  __shared__ unsigned Ww[64 * RW];
  const int t = threadIdx.x;
  const int nodeBase = blockIdx.x * 64;

  for (int i4 = t * 4; i4 < 64 * K; i4 += 1024) {
    int f = i4 >> 6, k = i4 & (K - 1);
    float4 v = *(const float4*)(W + ((long long)f << 6) + k);
    uint2 p = make_uint2(pk2(v.x, v.y), pk2(v.z, v.w));
    int kw = k >> 1;
    *(uint2*)&Ww[f * RW + (kw ^ ((f & 7) << 2))] = p;
  }

  const int fl = t & 7;
#pragma unroll
  for (int half = 0; half < 2; half++) {
    const int nl = half * 32 + (t >> 3);
    const int n = nodeBase + nl;
    const int sxa = (nl & 7) << 2;
    const int kwb = (4 * fl) ^ sxa;
    if (n < NN) {
      const float edn = edIn[n];
      const int row = rowptr[n];
      const int end = rowptr[n + 1];
      const int endm1 = end - 1;
      float den = 0.f;
      float acc[8];
#pragma unroll
      for (int j = 0; j < 8; j++) acc[j] = 0.f;
      for (int i = row; i < end; i += 4) {
        int k1 = i + 1, k2 = i + 2, k3 = i + 3;
        k1 = (k1 < end) ? k1 : endm1;
        k2 = (k2 < end) ? k2 : endm1;
        k3 = (k3 < end) ? k3 : endm1;
        int s0 = csr[i], s1 = csr[k1], s2 = csr[k2], s3 = csr[k3];
        uint2 u0 = h8In[s0 * 8 + fl];
        uint2 u1 = h8In[s1 * 8 + fl];
        uint2 u2 = h8In[s2 * 8 + fl];
        uint2 u3 = h8In[s3 * 8 + fl];
        float e0 = esIn[s0] + edn, e1 = esIn[s1] + edn;
        float e2 = esIn[s2] + edn, e3 = esIn[s3] + edn;
        e0 = fmaxf(e0, NEG * e0);
        e1 = fmaxf(e1, NEG * e1);
        e2 = fmaxf(e2, NEG * e2);
        e3 = fmaxf(e3, NEG * e3);
        float w0 = exp2f(e0), w1 = exp2f(e1), w2 = exp2f(e2), w3 = exp2f(e3);
        w1 = (i + 1 < end) ? w1 : 0.f;
        w2 = (i + 2 < end) ? w2 : 0.f;
        w3 = (i + 3 < end) ? w3 : 0.f;
        den += (w0 + w1) + (w2 + w3);
#define ACC_E(w, u)                                            \
        { floatx2 fA = unpk2_fp8<false>((u).x);                \
          floatx2 fB = unpk2_fp8<true>((u).x);                 \
          floatx2 fC = unpk2_fp8<false>((u).y);                \
          floatx2 fD = unpk2_fp8<true>((u).y);                 \
          acc[0] = fmaf(w, fA.x, acc[0]); acc[1] = fmaf(w, fA.y, acc[1]); \
          acc[2] = fmaf(w, fB.x, acc[2]); acc[3] = fmaf(w, fB.y, acc[3]); \
          acc[4] = fmaf(w, fC.x, acc[4]); acc[5] = fmaf(w, fC.y, acc[5]); \
          acc[6] = fmaf(w, fD.x, acc[6]); acc[7] = fmaf(w, fD.y, acc[7]); }
        ACC_E(w0, u0) ACC_E(w1, u1) ACC_E(w2, u2) ACC_E(w3, u3)
#undef ACC_E
      }
      const float inv = 1.0f / den;
      float v[8];
#pragma unroll
      for (int j = 0; j < 8; j++)
        v[j] = fmaxf(acc[j] * inv + biasA[8 * fl + j], 0.f);   // relu (layers 1,2)
      *(uint2*)&Xw[nl * RW + kwb] = make_uint2(pk2(v[0], v[1]), pk2(v[2], v[3]));
      *(uint2*)&Xw[nl * RW + kwb + 2] = make_uint2(pk2(v[4], v[5]), pk2(v[6], v[7]));
    } else {
      *(uint2*)&Xw[nl * RW + kwb] = make_uint2(0u, 0u);
      *(uint2*)&Xw[nl * RW + kwb + 2] = make_uint2(0u, 0u);
    }
  }
  __syncthreads();

  const int w = t >> 6, l = t & 63, m = l & 15, q = l >> 4;
  const int nodeLoc = 16 * w + m;
  const int sxa = (nodeLoc & 7) << 2;
  floatx4 acc[4];
#pragma unroll
  for (int nt = 0; nt < 4; nt++) acc[nt] = (floatx4){0.f, 0.f, 0.f, 0.f};
#pragma unroll
  for (int kc = 0; kc < K; kc += 32) {
    const int kcw = (kc >> 1) + 4 * q;
    short8 af = *(const short8*)&Xw[nodeLoc * RW + (kcw ^ sxa)];
#pragma unroll
    for (int nt = 0; nt < 4; nt++) {
      int f = 16 * nt + m;
      short8 bf = *(const short8*)&Ww[f * RW + (kcw ^ ((f & 7) << 2))];
      acc[nt] = __builtin_amdgcn_mfma_f32_16x16x32_bf16(af, bf, acc[nt], 0, 0, 0);
    }
  }
  float asv[4], adv[4];
#pragma unroll
  for (int nt = 0; nt < 4; nt++) { asv[nt] = As[16 * nt + m]; adv[nt] = Ad[16 * nt + m]; }
#pragma unroll
  for (int r = 0; r < 4; r++) {
    float ss = 0.f, sd2 = 0.f;
#pragma unroll
    for (int nt = 0; nt < 4; nt++) {
      ss = fmaf(acc[nt][r], asv[nt], ss);
      sd2 = fmaf(acc[nt][r], adv[nt], sd2);
    }
#pragma unroll
    for (int off = 1; off < 16; off <<= 1) {
      ss += __shfl_xor(ss, off);
      sd2 += __shfl_xor(sd2, off);
    }
    if (m == 0) {
      int gn = nodeBase + 16 * w + 4 * q + r;
      if (gn < NN) { esOut[gn] = ss * LOG2E; edOut[gn] = sd2 * LOG2E; }
    }
  }
  {
    int gn = nodeBase + 16 * w + 4 * q;
#pragma unroll
    for (int nt = 0; nt < 4; nt++) {
#pragma unroll
      for (int r = 0; r < 4; r++) {
        float v = acc[nt][r];
        float p1 = __shfl_xor(v, 1);
        float p2 = __shfl_xor(v, 2);
        float p3 = __shfl_xor(v, 3);
        if ((m & 3) == 0 && (gn + r) < NN)
          hOut[(gn + r) * 16 + 4 * nt + (m >> 2)] = pack4_fp8(v, p1, p2, p3);
      }
    }
  }
}

// ---------------- fused: aggregate layer 3 + mean-pool scatter ----------------
__global__ __launch_bounds__(256) void agg3_pool_kernel(
    const int* __restrict__ rowptr, const int* __restrict__ csr,
    const float* __restrict__ esIn, const float* __restrict__ edIn,
    const uint2* __restrict__ h8In, const float* __restrict__ biasA,
    const int* __restrict__ batch, float* __restrict__ pooled) {
  __shared__ float P[32 * 66];
  __shared__ int gl[32];
  const int t = threadIdx.x;
  const int fl = t & 7;
  const int nl = t >> 3;               // 0..31
  const int n = blockIdx.x * 32 + nl;  // NN = 3125*32 exactly
  if (t < 32) gl[t] = batch[blockIdx.x * 32 + t];
  {
    const float edn = edIn[n];
    const int row = rowptr[n];
    const int end = rowptr[n + 1];
    const int endm1 = end - 1;
    float den = 0.f;
    float acc[8];
#pragma unroll
    for (int j = 0; j < 8; j++) acc[j] = 0.f;
    for (int i = row; i < end; i += 4) {
      int k1 = i + 1, k2 = i + 2, k3 = i + 3;
      k1 = (k1 < end) ? k1 : endm1;
      k2 = (k2 < end) ? k2 : endm1;
      k3 = (k3 < end) ? k3 : endm1;
      int s0 = csr[i], s1 = csr[k1], s2 = csr[k2], s3 = csr[k3];
      uint2 u0 = h8In[s0 * 8 + fl];
      uint2 u1 = h8In[s1 * 8 + fl];
      uint2 u2 = h8In[s2 * 8 + fl];
      uint2 u3 = h8In[s3 * 8 + fl];
      float e0 = esIn[s0] + edn, e1 = esIn[s1] + edn;
      float e2 = esIn[s2] + edn, e3 = esIn[s3] + edn;
      e0 = fmaxf(e0, NEG * e0);
      e1 = fmaxf(e1, NEG * e1);
      e2 = fmaxf(e2, NEG * e2);
      e3 = fmaxf(e3, NEG * e3);
      float w0 = exp2f(e0), w1 = exp2f(e1), w2 = exp2f(e2), w3 = exp2f(e3);
      w1 = (i + 1 < end) ? w1 : 0.f;
      w2 = (i + 2 < end) ? w2 : 0.f;
      w3 = (i + 3 < end) ? w3 : 0.f;
      den += (w0 + w1) + (w2 + w3);
#define ACC_E(w, u)                                            \
      { floatx2 fA = unpk2_fp8<false>((u).x);                  \
        floatx2 fB = unpk2_fp8<true>((u).x);                   \
        floatx2 fC = unpk2_fp8<false>((u).y);                  \
        floatx2 fD = unpk2_fp8<true>((u).y);                   \
        acc[0] = fmaf(w, fA.x, acc[0]); acc[1] = fmaf(w, fA.y, acc[1]); \
        acc[2] = fmaf(w, fB.x, acc[2]); acc[3] = fmaf(w, fB.y, acc[3]); \
        acc[4] = fmaf(w, fC.x, acc[4]); acc[5] = fmaf(w, fC.y, acc[5]); \
        acc[6] = fmaf(w, fD.x, acc[6]); acc[7] = fmaf(w, fD.y, acc[7]); }
      ACC_E(w0, u0) ACC_E(w1, u1) ACC_E(w2, u2) ACC_E(w3, u3)
#undef ACC_E
    }
    const float inv = 1.0f / den;
#pragma unroll
    for (int j = 0; j < 8; j++)
      P[nl * 66 + 8 * fl + j] = acc[j] * inv + biasA[8 * fl + j];  // no relu (layer 3)
  }
  __syncthreads();
  if (t < HD) {
    const int f = t;
    float s = 0.f;
    int gcur = gl[0];
    for (int k = 0; k < 32; k++) {
      int g = gl[k];
      if (g != gcur) {
        atomicAdd(&pooled[gcur * HD + f], s);
        s = 0.f;
        gcur = g;
      }
      s += P[k * 66 + f];
    }
    atomicAdd(&pooled[gcur * HD + f], s);
  }
}

// ---------------- final linear ----------------
__device__ __forceinline__ int lower_bound_batch(const int* bt, int target) {
  int lo = 0, hi = NN;
  while (lo < hi) {
    int mid = (lo + hi) >> 1;
    if (bt[mid] < target) lo = mid + 1; else hi = mid;
  }
  return lo;
}

__global__ void final_kernel(
    const float* __restrict__ pooled, const int* __restrict__ batch,
    const float* __restrict__ Wlin, const float* __restrict__ blin,
    float* __restrict__ out) {
  int t = blockIdx.x * blockDim.x + threadIdx.x;
  if (t >= NB * NC) return;
  int b = t / NC, c = t - b * NC;
  int lo = lower_bound_batch(batch, b);
  int hi = lower_bound_batch(batch, b + 1);
  float inv = 1.0f / fmaxf((float)(hi - lo), 1.0f);
  float a = blin[c];
#pragma unroll 16
  for (int f = 0; f < HD; f++)
    a = fmaf(pooled[b * HD + f] * inv, Wlin[(long long)c * HD + f], a);
  out[t] = a;
}

extern "C" void kernel_launch(void* const* d_in, const int* in_sizes, int n_in,
                              void* d_out, int out_size, void* d_ws, size_t ws_size,
                              hipStream_t stream) {
  char* ws = (char*)d_ws;
  unsigned* hA       = (unsigned*)(ws + OFF_HA);
  unsigned* hB       = (unsigned*)(ws + OFF_HB);
  float*    esA      = (float*)(ws + OFF_ESA);
  float*    edA      = (float*)(ws + OFF_EDA);
  float*    esB      = (float*)(ws + OFF_ESB);
  float*    edB      = (float*)(ws + OFF_EDB);
  int*      rowptr   = (int*)(ws + OFF_ROW);
  int*      csr      = (int*)(ws + OFF_CSR);
  int*      gcur     = (int*)(ws + OFF_GC);
  float*    pooled   = (float*)(ws + OFF_POOL);
  unsigned* bucketed = (unsigned*)(ws + OFF_BKT);

  const float* X  = (const float*)d_in[0];
  const int*   EI = (const int*)d_in[1];     // int32
  const int*   BT = (const int*)d_in[2];     // int32
  const float* Wm[3] = {(const float*)d_in[3], (const float*)d_in[7], (const float*)d_in[11]};
  const float* As[3] = {(const float*)d_in[4], (const float*)d_in[8], (const float*)d_in[12]};
  const float* Ad[3] = {(const float*)d_in[5], (const float*)d_in[9], (const float*)d_in[13]};
  const float* Bb[3] = {(const float*)d_in[6], (const float*)d_in[10], (const float*)d_in[14]};
  const float* Wl = (const float*)d_in[15];
  const float* bl = (const float*)d_in[16];

  (void)hipMemsetAsync(gcur, 0, 1024 + (size_t)NB * HD * 4, stream);
  buildA_gemm1_kernel<<<ABLOCKS + GBLOCKS, 256, 0, stream>>>(
      EI, bucketed, gcur, X, Wm[0], As[0], Ad[0], hA, esA, edA);
  bucketB_kernel<<<NBKT, 1024, 0, stream>>>(bucketed, gcur, rowptr, csr);
  agg_gemm_kernel<<<GBLOCKS, 256, 0, stream>>>(
      rowptr, csr, esA, edA, (const uint2*)hA, Bb[0],
      Wm[1], As[1], Ad[1], hB, esB, edB);
  agg_gemm_kernel<<<GBLOCKS, 256, 0, stream>>>(
      rowptr, csr, esB, edB, (const uint2*)hB, Bb[1],
      Wm[2], As[2], Ad[2], hA, esA, edA);
  agg3_pool_kernel<<<NN / 32, 256, 0, stream>>>(
      rowptr, csr, esA, edA, (const uint2*)hA, Bb[2], BT, pooled);
  final_kernel<<<(NB * NC + 255) / 256, 256, 0, stream>>>(pooled, BT, Wl, bl, (float*)d_out);
}

// Round 20
// 284.781 us; speedup vs baseline: 1.0481x; 1.0481x over previous
//
#include <hip/hip_runtime.h>
#include <hip/hip_bf16.h>

#define NN 100000
#define EE 1600000
#define ETOT 1700000   // EE + NN self loops
#define FIN1 128
#define HD 64
#define NC 10
#define NB 128
#define NEG 0.2f
#define LOG2E 1.44269504f

#define NBKT 196       // ceil(NN/512)
#define BCAP 10240     // per-bucket capacity (mean 8673, sd ~93)
#define BLKE 4096      // edges per bucketA block (round-19 2048 regressed: fragmentation)
#define ABLOCKS ((ETOT + BLKE - 1) / BLKE)   // 416
#define GBLOCKS ((NN + 63) / 64)             // 1563

// Input dtypes: floats fp32, integers int32 (harness spec; round-16 verified).

// workspace layout (bytes)
static constexpr size_t OFF_HA   = 0;                                // 6.4 MB
static constexpr size_t OFF_HB   = (size_t)NN * HD;                  // 6.4 MB
static constexpr size_t OFF_ESA  = (size_t)NN * HD * 2;
static constexpr size_t OFF_EDA  = OFF_ESA + (size_t)NN * 4;
static constexpr size_t OFF_ESB  = OFF_EDA + (size_t)NN * 4;
static constexpr size_t OFF_EDB  = OFF_ESB + (size_t)NN * 4;
static constexpr size_t OFF_ROW  = OFF_EDB + (size_t)NN * 4;         // rowptr[NN+1]
static constexpr size_t OFF_CSR  = OFF_ROW + (size_t)(NN + 4) * 4;   // 6.8 MB
static constexpr size_t OFF_GC   = OFF_CSR + (size_t)ETOT * 4;       // 1024 B
static constexpr size_t OFF_POOL = OFF_GC + 1024;                    // 32 KB (gcur+pooled: one memset)
static constexpr size_t OFF_BKT  = OFF_POOL + (size_t)NB * HD * 4;   // 8.03 MB
// total ~29.8 MB

typedef __attribute__((ext_vector_type(8))) short short8;   // 8 bf16 = 4 VGPR
typedef __attribute__((ext_vector_type(4))) float floatx4;
typedef __attribute__((ext_vector_type(2))) float floatx2;

__device__ __forceinline__ unsigned short f2bf(float f) {
  unsigned u = __float_as_uint(f);
  if ((u & 0x7F800000u) == 0x7F800000u) return (unsigned short)(u >> 16);
  return (unsigned short)((u + 0x7FFFu + ((u >> 16) & 1u)) >> 16);
}
__device__ __forceinline__ unsigned pk2(float a, float b) {
  return (unsigned)f2bf(a) | ((unsigned)f2bf(b) << 16);
}

// ---- fp8 e4m3 pack/unpack (HW builtins on gfx950; manual fallback) ----
#if __has_builtin(__builtin_amdgcn_cvt_pk_fp8_f32) && __has_builtin(__builtin_amdgcn_cvt_pk_f32_fp8)
#define HW_FP8 1
#endif
__device__ __forceinline__ unsigned enc1_fp8(float f) {
  _Float16 hf = (_Float16)f;
  unsigned short b = __builtin_bit_cast(unsigned short, hf);
  unsigned s = ((unsigned)b >> 8) & 0x80u;
  int mag = b & 0x7fff;
  if (mag < 0x2380) return s;
  int r = mag + 0x3F + ((mag >> 7) & 1);
  int m = (r >> 7) - 64;
  if (m > 0x7E) m = 0x7E;
  return s | (unsigned)m;
}
__device__ __forceinline__ unsigned pack4_fp8(float a, float b, float c, float d) {
#ifdef HW_FP8
  int w = __builtin_amdgcn_cvt_pk_fp8_f32(a, b, 0, false);
  w = __builtin_amdgcn_cvt_pk_fp8_f32(c, d, w, true);
  return (unsigned)w;
#else
  return enc1_fp8(a) | (enc1_fp8(b) << 8) | (enc1_fp8(c) << 16) | (enc1_fp8(d) << 24);
#endif
}
__device__ __forceinline__ float dec1_fp8(unsigned byte) {
  unsigned short hb = (unsigned short)(((byte & 0x80u) << 8) | ((byte & 0x7fu) << 7));
  _Float16 hf = __builtin_bit_cast(_Float16, hb);
  return (float)hf * 256.0f;
}
template <bool HI>
__device__ __forceinline__ floatx2 unpk2_fp8(unsigned w) {
#ifdef HW_FP8
  return __builtin_amdgcn_cvt_pk_f32_fp8((int)w, HI);
#else
  unsigned s = HI ? (w >> 16) : w;
  floatx2 r; r.x = dec1_fp8(s & 0xffu); r.y = dec1_fp8((s >> 8) & 0xffu);
  return r;
#endif
}

// ---------------- bucketA body: LDS-staged, bucket-sorted COALESCED writes ----------------
// ROUND-20: rounds 18/19 show bucketA is write-transaction-bound (4096 random
// 4B stores/block -> 4096 line transactions; WRITE 15.9-17.7 MB vs 6.8 ideal).
// Sort block-locally into LDS, then copy out bucket runs with consecutive
// lanes -> consecutive addresses (~84 B runs, ~7x fewer transactions).
__device__ __forceinline__ void bucketA_body(
    int bid, const int* __restrict__ EI, unsigned* __restrict__ bucketed,
    int* __restrict__ gcur, char* smem) {
  unsigned* stage = (unsigned*)smem;                        // BLKE words   16 KB
  unsigned short* sb = (unsigned short*)(smem + BLKE * 4);  // BLKE shorts   8 KB
  int* cnt  = (int*)(smem + BLKE * 4 + BLKE * 2);           // NBKT
  int* lofs = cnt + NBKT;                                   // NBKT
  int* base = lofs + NBKT;                                  // NBKT
  int* sc   = base + NBKT;                                  // 256
  const int t = threadIdx.x;
  const long long start = (long long)bid * BLKE;
  long long rem = (long long)ETOT - start;
  const int V = (rem < BLKE) ? (int)rem : BLKE;
  unsigned pk[BLKE / 256];
  short bk[BLKE / 256];
  for (int i = t; i < NBKT; i += 256) cnt[i] = 0;
  __syncthreads();
#pragma unroll
  for (int j = 0; j < BLKE / 256; j++) {
    long long k = start + t + 256 * j;
    bk[j] = -1;
    if (k < ETOT) {
      int s, d;
      if (k < EE) { s = EI[k]; d = EI[(long long)EE + k]; }
      else        { s = d = (int)(k - EE); }
      int b = d >> 9;
      pk[j] = ((unsigned)s << 9) | (unsigned)(d & 511);
      bk[j] = (short)b;
      atomicAdd(&cnt[b], 1);
    }
  }
  __syncthreads();
  // exclusive scan of cnt -> lofs; reserve global space; reset cnt as cursor
  int own = (t < NBKT) ? cnt[t] : 0;
  sc[t] = own;
  __syncthreads();
  for (int off = 1; off < 256; off <<= 1) {
    int add = (t >= off) ? sc[t - off] : 0;
    __syncthreads();
    sc[t] += add;
    __syncthreads();
  }
  if (t < NBKT) {
    lofs[t] = sc[t] - own;
    base[t] = (own > 0) ? atomicAdd(&gcur[t], own) : 0;
    cnt[t] = 0;
  }
  __syncthreads();
  // scatter into LDS staging (sorted by bucket)
#pragma unroll
  for (int j = 0; j < BLKE / 256; j++) {
    if (bk[j] >= 0) {
      int b = bk[j];
      int p = lofs[b] + atomicAdd(&cnt[b], 1);
      stage[p] = pk[j];
      sb[p] = (unsigned short)b;
    }
  }
  __syncthreads();
  // coalesced copy-out: entry i -> bucketed[b*BCAP + base[b] + (i - lofs[b])]
  for (int i = t; i < V; i += 256) {
    int b = sb[i];
    int pos = base[b] + (i - lofs[b]);
    if (pos < BCAP) bucketed[(long long)b * BCAP + pos] = stage[i];
  }
}

// ---------------- gemm1 body: h1 = x@W1^T from fp32 input (MFMA) ----------------
__device__ __forceinline__ void gemm1_body(
    int bid, const float* __restrict__ X, const float* __restrict__ W,
    const float* __restrict__ As, const float* __restrict__ Ad,
    unsigned* __restrict__ hout, float* __restrict__ es, float* __restrict__ ed,
    char* smem) {
  constexpr int K = FIN1, RW = K / 2;
  unsigned* Xw = (unsigned*)smem;             // 16 KB
  unsigned* Ww = (unsigned*)(smem + 16384);   // 16 KB
  const int t = threadIdx.x;
  const int nodeBase = bid * 64;

  for (int i4 = t * 4; i4 < 64 * K; i4 += 1024) {
    int node = i4 >> 7, k = i4 & (K - 1);
    float4 v = make_float4(0.f, 0.f, 0.f, 0.f);
    if (nodeBase + node < NN)
      v = *(const float4*)(X + ((long long)(nodeBase + node) << 7) + k);
    uint2 p = make_uint2(pk2(v.x, v.y), pk2(v.z, v.w));
    int kw = k >> 1;
    *(uint2*)&Xw[node * RW + (kw ^ ((node & 7) << 2))] = p;
  }
  for (int i4 = t * 4; i4 < 64 * K; i4 += 1024) {
    int f = i4 >> 7, k = i4 & (K - 1);
    float4 v = *(const float4*)(W + ((long long)f << 7) + k);
    uint2 p = make_uint2(pk2(v.x, v.y), pk2(v.z, v.w));
    int kw = k >> 1;
    *(uint2*)&Ww[f * RW + (kw ^ ((f & 7) << 2))] = p;
  }
  __syncthreads();

  const int w = t >> 6, l = t & 63, m = l & 15, q = l >> 4;
  const int nodeLoc = 16 * w + m;
  const int sxa = (nodeLoc & 7) << 2;
  floatx4 acc[4];
#pragma unroll
  for (int nt = 0; nt < 4; nt++) acc[nt] = (floatx4){0.f, 0.f, 0.f, 0.f};
#pragma unroll
  for (int kc = 0; kc < K; kc += 32) {
    const int kcw = (kc >> 1) + 4 * q;
    short8 af = *(const short8*)&Xw[nodeLoc * RW + (kcw ^ sxa)];
#pragma unroll
    for (int nt = 0; nt < 4; nt++) {
      int f = 16 * nt + m;
      short8 bf = *(const short8*)&Ww[f * RW + (kcw ^ ((f & 7) << 2))];
      acc[nt] = __builtin_amdgcn_mfma_f32_16x16x32_bf16(af, bf, acc[nt], 0, 0, 0);
    }
  }
  float asv[4], adv[4];
#pragma unroll
  for (int nt = 0; nt < 4; nt++) { asv[nt] = As[16 * nt + m]; adv[nt] = Ad[16 * nt + m]; }
#pragma unroll
  for (int r = 0; r < 4; r++) {
    float ss = 0.f, sd2 = 0.f;
#pragma unroll
    for (int nt = 0; nt < 4; nt++) {
      ss = fmaf(acc[nt][r], asv[nt], ss);
      sd2 = fmaf(acc[nt][r], adv[nt], sd2);
    }
#pragma unroll
    for (int off = 1; off < 16; off <<= 1) {
      ss += __shfl_xor(ss, off);
      sd2 += __shfl_xor(sd2, off);
    }
    if (m == 0) {
      int gn = nodeBase + 16 * w + 4 * q + r;
      if (gn < NN) { es[gn] = ss * LOG2E; ed[gn] = sd2 * LOG2E; }
    }
  }
  {
    int gn = nodeBase + 16 * w + 4 * q;
#pragma unroll
    for (int nt = 0; nt < 4; nt++) {
#pragma unroll
      for (int r = 0; r < 4; r++) {
        float v = acc[nt][r];
        float p1 = __shfl_xor(v, 1);
        float p2 = __shfl_xor(v, 2);
        float p3 = __shfl_xor(v, 3);
        if ((m & 3) == 0 && (gn + r) < NN)
          hout[(gn + r) * 16 + 4 * nt + (m >> 2)] = pack4_fp8(v, p1, p2, p3);
      }
    }
  }
}

// ---------------- fused dispatch: bucketA ∥ gemm1 (grid concatenation) ----------------
__global__ __launch_bounds__(256) void buildA_gemm1_kernel(
    const int* __restrict__ EI, unsigned* __restrict__ bucketed, int* __restrict__ gcur,
    const float* __restrict__ X, const float* __restrict__ W,
    const float* __restrict__ As, const float* __restrict__ Ad,
    unsigned* __restrict__ hout, float* __restrict__ es, float* __restrict__ ed) {
  __shared__ __align__(16) char smem[32768];
  if (blockIdx.x < ABLOCKS)
    bucketA_body(blockIdx.x, EI, bucketed, gcur, smem);
  else
    gemm1_body(blockIdx.x - ABLOCKS, X, W, As, Ad, hout, es, ed, smem);
}

// ---------------- bucketB: 1024 threads (4x latency hiding), inline scan ----------------
__global__ __launch_bounds__(1024) void bucketB_kernel(
    const unsigned* __restrict__ bucketed, const int* __restrict__ gcur,
    int* __restrict__ rowptr, int* __restrict__ csr) {
  __shared__ int sc[256];
  __shared__ int hist[512];
  __shared__ int cur[512];
  __shared__ int ssum[256];
  const int t = threadIdx.x;
  const int b = blockIdx.x;
  if (t < 256) sc[t] = (t < NBKT) ? gcur[t] : 0;
  __syncthreads();
  for (int off = 1; off < 256; off <<= 1) {
    int add = (t >= off && t < 256) ? sc[t - off] : 0;
    __syncthreads();
    if (t < 256) sc[t] += add;
    __syncthreads();
  }
  const int cnt = gcur[b];
  const int base = sc[b] - cnt;
  if (b == 0 && t == 0) rowptr[NN] = ETOT;
  const unsigned* bp = bucketed + (long long)b * BCAP;
  if (t < 512) hist[t] = 0;
  __syncthreads();
  for (int i = t; i < cnt; i += 1024) atomicAdd(&hist[bp[i] & 511], 1);
  __syncthreads();
  int a0 = 0, a1 = 0, s = 0;
  if (t < 256) {
    a0 = hist[2 * t];
    a1 = hist[2 * t + 1];
    s = a0 + a1;
    ssum[t] = s;
  }
  __syncthreads();
  for (int off = 1; off < 256; off <<= 1) {
    int add = (t >= off && t < 256) ? ssum[t - off] : 0;
    __syncthreads();
    if (t < 256) ssum[t] += add;
    __syncthreads();
  }
  if (t < 256) {
    int ex = ssum[t] - s;
    cur[2 * t] = ex;
    cur[2 * t + 1] = ex + a0;
    int gn = b * 512 + 2 * t;
    if (gn < NN) rowptr[gn] = base + ex;
    if (gn + 1 < NN) rowptr[gn + 1] = base + ex + a0;
  }
  __syncthreads();
  for (int i = t; i < cnt; i += 1024) {
    unsigned e = bp[i];
    int pos = atomicAdd(&cur[e & 511], 1);
    csr[base + pos] = (int)(e >> 9);
  }
}

// ---------------- fused: aggregate layer L -> LDS -> gemm layer L+1 ----------------
__global__ __launch_bounds__(256) void agg_gemm_kernel(
    const int* __restrict__ rowptr, const int* __restrict__ csr,
    const float* __restrict__ esIn, const float* __restrict__ edIn,
    const uint2* __restrict__ h8In, const float* __restrict__ biasA,
    const float* __restrict__ W, const float* __restrict__ As,
    const float* __restrict__ Ad,
    unsigned* __restrict__ hOut, float* __restrict__ esOut, float* __restrict__ edOut) {
  constexpr int K = HD, RW = K / 2;   // 64, 32
  __shared__ unsigned Xw[64 * RW];
  __shared__ unsigned Ww[64 * RW];
  const int t = threadIdx.x;
  const int nodeBase = blockIdx.x * 64;

  for (int i4 = t * 4; i4 < 64 * K; i4 += 1024) {
    int f = i4 >> 6, k = i4 & (K - 1);
    float4 v = *(const float4*)(W + ((long long)f << 6) + k);
    uint2 p = make_uint2(pk2(v.x, v.y), pk2(v.z, v.w));
    int kw = k >> 1;
    *(uint2*)&Ww[f * RW + (kw ^ ((f & 7) << 2))] = p;
  }

  const int fl = t & 7;
#pragma unroll
  for (int half = 0; half < 2; half++) {
    const int nl = half * 32 + (t >> 3);
    const int n = nodeBase + nl;
    const int sxa = (nl & 7) << 2;
    const int kwb = (4 * fl) ^ sxa;
    if (n < NN) {
      const float edn = edIn[n];
      const int row = rowptr[n];
      const int end = rowptr[n + 1];
      const int endm1 = end - 1;
      float den = 0.f;
      float acc[8];
#pragma unroll
      for (int j = 0; j < 8; j++) acc[j] = 0.f;
      for (int i = row; i < end; i += 4) {
        int k1 = i + 1, k2 = i + 2, k3 = i + 3;
        k1 = (k1 < end) ? k1 : endm1;
        k2 = (k2 < end) ? k2 : endm1;
        k3 = (k3 < end) ? k3 : endm1;
        int s0 = csr[i], s1 = csr[k1], s2 = csr[k2], s3 = csr[k3];
        uint2 u0 = h8In[s0 * 8 + fl];
        uint2 u1 = h8In[s1 * 8 + fl];
        uint2 u2 = h8In[s2 * 8 + fl];
        uint2 u3 = h8In[s3 * 8 + fl];
        float e0 = esIn[s0] + edn, e1 = esIn[s1] + edn;
        float e2 = esIn[s2] + edn, e3 = esIn[s3] + edn;
        e0 = fmaxf(e0, NEG * e0);
        e1 = fmaxf(e1, NEG * e1);
        e2 = fmaxf(e2, NEG * e2);
        e3 = fmaxf(e3, NEG * e3);
        float w0 = exp2f(e0), w1 = exp2f(e1), w2 = exp2f(e2), w3 = exp2f(e3);
        w1 = (i + 1 < end) ? w1 : 0.f;
        w2 = (i + 2 < end) ? w2 : 0.f;
        w3 = (i + 3 < end) ? w3 : 0.f;
        den += (w0 + w1) + (w2 + w3);
#define ACC_E(w, u)                                            \
        { floatx2 fA = unpk2_fp8<false>((u).x);                \
          floatx2 fB = unpk2_fp8<true>((u).x);                 \
          floatx2 fC = unpk2_fp8<false>((u).y);                \
          floatx2 fD = unpk2_fp8<true>((u).y);                 \
          acc[0] = fmaf(w, fA.x, acc[0]); acc[1] = fmaf(w, fA.y, acc[1]); \
          acc[2] = fmaf(w, fB.x, acc[2]); acc[3] = fmaf(w, fB.y, acc[3]); \
          acc[4] = fmaf(w, fC.x, acc[4]); acc[5] = fmaf(w, fC.y, acc[5]); \
          acc[6] = fmaf(w, fD.x, acc[6]); acc[7] = fmaf(w, fD.y, acc[7]); }
        ACC_E(w0, u0) ACC_E(w1, u1) ACC_E(w2, u2) ACC_E(w3, u3)
#undef ACC_E
      }
      const float inv = 1.0f / den;
      float v[8];
#pragma unroll
      for (int j = 0; j < 8; j++)
        v[j] = fmaxf(acc[j] * inv + biasA[8 * fl + j], 0.f);   // relu (layers 1,2)
      *(uint2*)&Xw[nl * RW + kwb] = make_uint2(pk2(v[0], v[1]), pk2(v[2], v[3]));
      *(uint2*)&Xw[nl * RW + kwb + 2] = make_uint2(pk2(v[4], v[5]), pk2(v[6], v[7]));
    } else {
      *(uint2*)&Xw[nl * RW + kwb] = make_uint2(0u, 0u);
      *(uint2*)&Xw[nl * RW + kwb + 2] = make_uint2(0u, 0u);
    }
  }
  __syncthreads();

  const int w = t >> 6, l = t & 63, m = l & 15, q = l >> 4;
  const int nodeLoc = 16 * w + m;
  const int sxa = (nodeLoc & 7) << 2;
  floatx4 acc[4];
#pragma unroll
  for (int nt = 0; nt < 4; nt++) acc[nt] = (floatx4){0.f, 0.f, 0.f, 0.f};
#pragma unroll
  for (int kc = 0; kc < K; kc += 32) {
    const int kcw = (kc >> 1) + 4 * q;
    short8 af = *(const short8*)&Xw[nodeLoc * RW + (kcw ^ sxa)];
#pragma unroll
    for (int nt = 0; nt < 4; nt++) {
      int f = 16 * nt + m;
      short8 bf = *(const short8*)&Ww[f * RW + (kcw ^ ((f & 7) << 2))];
      acc[nt] = __builtin_amdgcn_mfma_f32_16x16x32_bf16(af, bf, acc[nt], 0, 0, 0);
    }
  }
  float asv[4], adv[4];
#pragma unroll
  for (int nt = 0; nt < 4; nt++) { asv[nt] = As[16 * nt + m]; adv[nt] = Ad[16 * nt + m]; }
#pragma unroll
  for (int r = 0; r < 4; r++) {
    float ss = 0.f, sd2 = 0.f;
#pragma unroll
    for (int nt = 0; nt < 4; nt++) {
      ss = fmaf(acc[nt][r], asv[nt], ss);
      sd2 = fmaf(acc[nt][r], adv[nt], sd2);
    }
#pragma unroll
    for (int off = 1; off < 16; off <<= 1) {
      ss += __shfl_xor(ss, off);
      sd2 += __shfl_xor(sd2, off);
    }
    if (m == 0) {
      int gn = nodeBase + 16 * w + 4 * q + r;
      if (gn < NN) { esOut[gn] = ss * LOG2E; edOut[gn] = sd2 * LOG2E; }
    }
  }
  {
    int gn = nodeBase + 16 * w + 4 * q;
#pragma unroll
    for (int nt = 0; nt < 4; nt++) {
#pragma unroll
      for (int r = 0; r < 4; r++) {
        float v = acc[nt][r];
        float p1 = __shfl_xor(v, 1);
        float p2 = __shfl_xor(v, 2);
        float p3 = __shfl_xor(v, 3);
        if ((m & 3) == 0 && (gn + r) < NN)
          hOut[(gn + r) * 16 + 4 * nt + (m >> 2)] = pack4_fp8(v, p1, p2, p3);
      }
    }
  }
}

// ---------------- fused: aggregate layer 3 + mean-pool scatter ----------------
__global__ __launch_bounds__(256) void agg3_pool_kernel(
    const int* __restrict__ rowptr, const int* __restrict__ csr,
    const float* __restrict__ esIn, const float* __restrict__ edIn,
    const uint2* __restrict__ h8In, const float* __restrict__ biasA,
    const int* __restrict__ batch, float* __restrict__ pooled) {
  __shared__ float P[32 * 66];
  __shared__ int gl[32];
  const int t = threadIdx.x;
  const int fl = t & 7;
  const int nl = t >> 3;               // 0..31
  const int n = blockIdx.x * 32 + nl;  // NN = 3125*32 exactly
  if (t < 32) gl[t] = batch[blockIdx.x * 32 + t];
  {
    const float edn = edIn[n];
    const int row = rowptr[n];
    const int end = rowptr[n + 1];
    const int endm1 = end - 1;
    float den = 0.f;
    float acc[8];
#pragma unroll
    for (int j = 0; j < 8; j++) acc[j] = 0.f;
    for (int i = row; i < end; i += 4) {
      int k1 = i + 1, k2 = i + 2, k3 = i + 3;
      k1 = (k1 < end) ? k1 : endm1;
      k2 = (k2 < end) ? k2 : endm1;
      k3 = (k3 < end) ? k3 : endm1;
      int s0 = csr[i], s1 = csr[k1], s2 = csr[k2], s3 = csr[k3];
      uint2 u0 = h8In[s0 * 8 + fl];
      uint2 u1 = h8In[s1 * 8 + fl];
      uint2 u2 = h8In[s2 * 8 + fl];
      uint2 u3 = h8In[s3 * 8 + fl];
      float e0 = esIn[s0] + edn, e1 = esIn[s1] + edn;
      float e2 = esIn[s2] + edn, e3 = esIn[s3] + edn;
      e0 = fmaxf(e0, NEG * e0);
      e1 = fmaxf(e1, NEG * e1);
      e2 = fmaxf(e2, NEG * e2);
      e3 = fmaxf(e3, NEG * e3);
      float w0 = exp2f(e0), w1 = exp2f(e1), w2 = exp2f(e2), w3 = exp2f(e3);
      w1 = (i + 1 < end) ? w1 : 0.f;
      w2 = (i + 2 < end) ? w2 : 0.f;
      w3 = (i + 3 < end) ? w3 : 0.f;
      den += (w0 + w1) + (w2 + w3);
#define ACC_E(w, u)                                            \
      { floatx2 fA = unpk2_fp8<false>((u).x);                  \
        floatx2 fB = unpk2_fp8<true>((u).x);                   \
        floatx2 fC = unpk2_fp8<false>((u).y);                  \
        floatx2 fD = unpk2_fp8<true>((u).y);                   \
        acc[0] = fmaf(w, fA.x, acc[0]); acc[1] = fmaf(w, fA.y, acc[1]); \
        acc[2] = fmaf(w, fB.x, acc[2]); acc[3] = fmaf(w, fB.y, acc[3]); \
        acc[4] = fmaf(w, fC.x, acc[4]); acc[5] = fmaf(w, fC.y, acc[5]); \
        acc[6] = fmaf(w, fD.x, acc[6]); acc[7] = fmaf(w, fD.y, acc[7]); }
      ACC_E(w0, u0) ACC_E(w1, u1) ACC_E(w2, u2) ACC_E(w3, u3)
#undef ACC_E
    }
    const float inv = 1.0f / den;
#pragma unroll
    for (int j = 0; j < 8; j++)
      P[nl * 66 + 8 * fl + j] = acc[j] * inv + biasA[8 * fl + j];  // no relu (layer 3)
  }
  __syncthreads();
  if (t < HD) {
    const int f = t;
    float s = 0.f;
    int gcur = gl[0];
    for (int k = 0; k < 32; k++) {
      int g = gl[k];
      if (g != gcur) {
        atomicAdd(&pooled[gcur * HD + f], s);
        s = 0.f;
        gcur = g;
      }
      s += P[k * 66 + f];
    }
    atomicAdd(&pooled[gcur * HD + f], s);
  }
}

// ---------------- final linear ----------------
__device__ __forceinline__ int lower_bound_batch(const int* bt, int target) {
  int lo = 0, hi = NN;
  while (lo < hi) {
    int mid = (lo + hi) >> 1;
    if (bt[mid] < target) lo = mid + 1; else hi = mid;
  }
  return lo;
}

__global__ void final_kernel(
    const float* __restrict__ pooled, const int* __restrict__ batch,
    const float* __restrict__ Wlin, const float* __restrict__ blin,
    float* __restrict__ out) {
  int t = blockIdx.x * blockDim.x + threadIdx.x;
  if (t >= NB * NC) return;
  int b = t / NC, c = t - b * NC;
  int lo = lower_bound_batch(batch, b);
  int hi = lower_bound_batch(batch, b + 1);
  float inv = 1.0f / fmaxf((float)(hi - lo), 1.0f);
  float a = blin[c];
#pragma unroll 16
  for (int f = 0; f < HD; f++)
    a = fmaf(pooled[b * HD + f] * inv, Wlin[(long long)c * HD + f], a);
  out[t] = a;
}

extern "C" void kernel_launch(void* const* d_in, const int* in_sizes, int n_in,
                              void* d_out, int out_size, void* d_ws, size_t ws_size,
                              hipStream_t stream) {
  char* ws = (char*)d_ws;
  unsigned* hA       = (unsigned*)(ws + OFF_HA);
  unsigned* hB       = (unsigned*)(ws + OFF_HB);
  float*    esA      = (float*)(ws + OFF_ESA);
  float*    edA      = (float*)(ws + OFF_EDA);
  float*    esB      = (float*)(ws + OFF_ESB);
  float*    edB      = (float*)(ws + OFF_EDB);
  int*      rowptr   = (int*)(ws + OFF_ROW);
  int*      csr      = (int*)(ws + OFF_CSR);
  int*      gcur     = (int*)(ws + OFF_GC);
  float*    pooled   = (float*)(ws + OFF_POOL);
  unsigned* bucketed = (unsigned*)(ws + OFF_BKT);

  const float* X  = (const float*)d_in[0];
  const int*   EI = (const int*)d_in[1];     // int32
  const int*   BT = (const int*)d_in[2];     // int32
  const float* Wm[3] = {(const float*)d_in[3], (const float*)d_in[7], (const float*)d_in[11]};
  const float* As[3] = {(const float*)d_in[4], (const float*)d_in[8], (const float*)d_in[12]};
  const float* Ad[3] = {(const float*)d_in[5], (const float*)d_in[9], (const float*)d_in[13]};
  const float* Bb[3] = {(const float*)d_in[6], (const float*)d_in[10], (const float*)d_in[14]};
  const float* Wl = (const float*)d_in[15];
  const float* bl = (const float*)d_in[16];

  (void)hipMemsetAsync(gcur, 0, 1024 + (size_t)NB * HD * 4, stream);
  buildA_gemm1_kernel<<<ABLOCKS + GBLOCKS, 256, 0, stream>>>(
      EI, bucketed, gcur, X, Wm[0], As[0], Ad[0], hA, esA, edA);
  bucketB_kernel<<<NBKT, 1024, 0, stream>>>(bucketed, gcur, rowptr, csr);
  agg_gemm_kernel<<<GBLOCKS, 256, 0, stream>>>(
      rowptr, csr, esA, edA, (const uint2*)hA, Bb[0],
      Wm[1], As[1], Ad[1], hB, esB, edB);
  agg_gemm_kernel<<<GBLOCKS, 256, 0, stream>>>(
      rowptr, csr, esB, edB, (const uint2*)hB, Bb[1],
      Wm[2], As[2], Ad[2], hA, esA, edA);
  agg3_pool_kernel<<<NN / 32, 256, 0, stream>>>(
      rowptr, csr, esA, edA, (const uint2*)hA, Bb[2], BT, pooled);
  final_kernel<<<(NB * NC + 255) / 256, 256, 0, stream>>>(pooled, BT, Wl, bl, (float*)d_out);
}